// Round 3
// baseline (543.239 us; speedup 1.0000x reference)
//
#include <hip/hip_runtime.h>
#include <hip/hip_bf16.h>
#include <stdint.h>

#define N_TOK 16384
#define D_IN  2048
#define D_HID 2048

typedef __attribute__((ext_vector_type(8))) short  bf16x8;
typedef __attribute__((ext_vector_type(4))) float  f32x4;
typedef __attribute__((ext_vector_type(8))) unsigned short u16x8;

__device__ __forceinline__ unsigned short f2bf(float f) {
    unsigned int u = __float_as_uint(f);
    u = (u + 0x7FFFu + ((u >> 16) & 1u)) >> 16;
    return (unsigned short)u;
}

// ---------------------------------------------- fused gate + x->bf16 ----
// One block per token: load row once, emit bf16 row, compute 8-expert
// logits + softmax + top-2 in the same pass (saves a full 134 MB x read).
__global__ __launch_bounds__(256) void gate_xconv_kernel(
    const float* __restrict__ x,
    const float* __restrict__ Wg,
    const float* __restrict__ bg,
    unsigned short* __restrict__ xb,
    float* __restrict__ s12,
    int* __restrict__ eidx) {
    __shared__ float red[4][8];
    const int token = blockIdx.x;
    const int tid   = threadIdx.x;
    const int lane  = tid & 63;
    const int w     = tid >> 6;
    const float* xr = x + (size_t)token * D_IN + tid * 8;

    float4 v0 = *(const float4*)xr;
    float4 v1 = *(const float4*)(xr + 4);
    float xv[8] = {v0.x, v0.y, v0.z, v0.w, v1.x, v1.y, v1.z, v1.w};

    u16x8 o;
#pragma unroll
    for (int j = 0; j < 8; ++j) o[j] = f2bf(xv[j]);
    *(u16x8*)(xb + (size_t)token * D_IN + tid * 8) = o;

    float acc[8];
#pragma unroll
    for (int e = 0; e < 8; ++e) acc[e] = 0.f;
#pragma unroll
    for (int j = 0; j < 8; ++j) {
        const float4* wr = (const float4*)(Wg + (size_t)(tid * 8 + j) * 8);
        float4 w0 = wr[0], w1 = wr[1];
        acc[0] += xv[j] * w0.x; acc[1] += xv[j] * w0.y;
        acc[2] += xv[j] * w0.z; acc[3] += xv[j] * w0.w;
        acc[4] += xv[j] * w1.x; acc[5] += xv[j] * w1.y;
        acc[6] += xv[j] * w1.z; acc[7] += xv[j] * w1.w;
    }
#pragma unroll
    for (int off = 32; off > 0; off >>= 1) {
#pragma unroll
        for (int e = 0; e < 8; ++e) acc[e] += __shfl_xor(acc[e], off);
    }
    if (lane == 0) {
#pragma unroll
        for (int e = 0; e < 8; ++e) red[w][e] = acc[e];
    }
    __syncthreads();
    if (tid == 0) {
        float lg[8];
        float mx = -1e30f;
#pragma unroll
        for (int e = 0; e < 8; ++e) {
            lg[e] = red[0][e] + red[1][e] + red[2][e] + red[3][e] + bg[e];
            mx = fmaxf(mx, lg[e]);
        }
        float sum = 0.f;
#pragma unroll
        for (int e = 0; e < 8; ++e) { lg[e] = expf(lg[e] - mx); sum += lg[e]; }
        float inv = 1.f / sum;
        float s1 = -1.f, s2 = -1.f; int i1 = 0, i2 = 0;
#pragma unroll
        for (int e = 0; e < 8; ++e) {
            float g = lg[e] * inv;
            if (g > s1)      { s2 = s1; i2 = i1; s1 = g; i1 = e; }
            else if (g > s2) { s2 = g;  i2 = e; }
        }
        s12[token * 2]     = s1;
        s12[token * 2 + 1] = s2;
        if (token == 0) { eidx[0] = i1; eidx[1] = i2; }
    }
}

// --------------------------------------- W[e0],W[e1] -> bf16 transposed --
__global__ void wconv_kernel(const float* __restrict__ W,
                             const int* __restrict__ eidx,
                             unsigned short* __restrict__ wbT) {
    __shared__ float tile[64][65];
    const int slot = blockIdx.z;
    const int e    = eidx[slot];
    const int k0   = blockIdx.y * 64;
    const int n0   = blockIdx.x * 64;
    const float* src = W + (size_t)e * D_IN * D_HID;
    const int t = threadIdx.x;

#pragma unroll
    for (int p = 0; p < 4; ++p) {
        int row = p * 16 + (t >> 4);
        int col = (t & 15) * 4;
        const float* s = src + (size_t)(k0 + row) * D_HID + n0 + col;
        tile[row][col]     = s[0];
        tile[row][col + 1] = s[1];
        tile[row][col + 2] = s[2];
        tile[row][col + 3] = s[3];
    }
    __syncthreads();

    unsigned short* dst = wbT + (size_t)slot * D_IN * D_HID;
#pragma unroll
    for (int p = 0; p < 2; ++p) {
        int n = p * 32 + (t >> 3);
        int g = (t & 7) * 8;
        u16x8 v;
#pragma unroll
        for (int j = 0; j < 8; ++j) v[j] = f2bf(tile[g + j][n]);
        *(u16x8*)(dst + (size_t)(n0 + n) * D_IN + k0 + g) = v;
    }
}

// ------------------------------------------------------------------ GEMM --
// 256 rows x (128 cols x 2 experts), BK=32, 4 LDS buffers, depth-3 counted
// vmcnt (8 -> 4 -> 0 tail), 2 phases/K-tile of 16 MFMA. ds_reads issued
// BEFORE the phase barrier, lgkmcnt(0) AFTER it (latency hides under the
// barrier wait); sched_barrier(0) pins both sides (rule #18).
#define GLD16(gp, lp)                                                        \
    __builtin_amdgcn_global_load_lds(                                        \
        (const __attribute__((address_space(1))) void*)(gp),                 \
        (__attribute__((address_space(3))) void*)(lp), 16, 0, 0)

#define LDSV(SLOT) (*(const bf16x8*)&lds[(SLOT) * 8])

#define STAGE_A(SBAS, KOFF)                                                  \
    do {                                                                     \
        GLD16(gA0 + (KOFF),      &lds[((SBAS) + wslot) * 8]);                \
        GLD16(gA0 + (KOFF) + 16, &lds[((SBAS) + 512 + wslot) * 8]);          \
    } while (0)
#define STAGE_B(SBAS, KOFF)                                                  \
    do {                                                                     \
        GLD16(gB0 + (KOFF),      &lds[((SBAS) + 1024 + wslot) * 8]);         \
        GLD16(gB0 + (KOFF) + 16, &lds[((SBAS) + 1536 + wslot) * 8]);         \
    } while (0)

#define MF(MI, AV)                                                                              \
    acc[MI][0] = __builtin_amdgcn_mfma_f32_16x16x32_bf16(AV, bf0, acc[MI][0], 0, 0, 0);         \
    acc[MI][1] = __builtin_amdgcn_mfma_f32_16x16x32_bf16(AV, bf1, acc[MI][1], 0, 0, 0);         \
    acc[MI][2] = __builtin_amdgcn_mfma_f32_16x16x32_bf16(AV, bf2, acc[MI][2], 0, 0, 0);         \
    acc[MI][3] = __builtin_amdgcn_mfma_f32_16x16x32_bf16(AV, bf3, acc[MI][3], 0, 0, 0);

// One K-tile: phase1 {read B0-3,A0-3 | STAGE_A | bar | lgkm0 | 16 MFMA},
//             phase2 {read A4-7 | STAGE_B | vmcnt(N) | bar | lgkm0 | 16 MFMA}
#define TILE(RB, SB, KOFF, DO_STAGE, VMSTR)                                  \
    do {                                                                     \
        const int rbas  = (RB) * 2048;                                       \
        const int abase = rbas + aks + arow;                                 \
        const int bbase = rbas + 1024 + aks + brow;                          \
        bf16x8 bf0 = LDSV(bbase), bf1 = LDSV(bbase + 16),                    \
               bf2 = LDSV(bbase + 32), bf3 = LDSV(bbase + 48);               \
        bf16x8 a0 = LDSV(abase), a1 = LDSV(abase + 16),                      \
               a2 = LDSV(abase + 32), a3 = LDSV(abase + 48);                 \
        if (DO_STAGE) STAGE_A((SB) * 2048, KOFF);                            \
        __builtin_amdgcn_sched_barrier(0);                                   \
        __builtin_amdgcn_s_barrier();                                        \
        asm volatile("s_waitcnt lgkmcnt(0)" ::: "memory");                   \
        __builtin_amdgcn_sched_barrier(0);                                   \
        __builtin_amdgcn_s_setprio(1);                                       \
        MF(0, a0) MF(1, a1) MF(2, a2) MF(3, a3)                              \
        __builtin_amdgcn_s_setprio(0);                                       \
        bf16x8 a4 = LDSV(abase + 64), a5 = LDSV(abase + 80),                 \
               a6 = LDSV(abase + 96), a7 = LDSV(abase + 112);                \
        if (DO_STAGE) STAGE_B((SB) * 2048, KOFF);                            \
        asm volatile(VMSTR ::: "memory");                                    \
        __builtin_amdgcn_sched_barrier(0);                                   \
        __builtin_amdgcn_s_barrier();                                        \
        asm volatile("s_waitcnt lgkmcnt(0)" ::: "memory");                   \
        __builtin_amdgcn_sched_barrier(0);                                   \
        __builtin_amdgcn_s_setprio(1);                                       \
        MF(4, a4) MF(5, a5) MF(6, a6) MF(7, a7)                              \
        __builtin_amdgcn_s_setprio(0);                                       \
    } while (0)

__global__ __launch_bounds__(512, 2) void moe_gemm_kernel(
    const unsigned short* __restrict__ xb,   // [N_TOK][D_IN] bf16
    const unsigned short* __restrict__ wbT,  // [2][D_HID][D_IN] bf16 (B^T)
    const float* __restrict__ b_exp,         // [8][D_HID]
    const int* __restrict__ eidx,
    const float* __restrict__ s12,           // [N_TOK][2]
    float* __restrict__ out) {
    // 4 buffers x (A:1024 + B:1024 slots) x 16B = 128 KiB
    __shared__ __align__(16) short lds[4 * 2048 * 8];

    const int t512 = threadIdx.x;
    const int lane = t512 & 63;
    const int w    = t512 >> 6;
    const int wm   = w >> 2;      // 0..1 : row half
    const int wn   = w & 3;       // 0..1 expert0 cols, 2..3 expert1 cols
    const int wslot = w * 64;

    // XCD-aware bijective swizzle (1024 % 8 == 0)
    const int bid = blockIdx.x;
    const int wg  = (bid & 7) * 128 + (bid >> 3);
    const int by  = wg >> 4;                  // 64 M-tiles
    const int bx  = wg & 15;                  // 16 col-tiles
    const int mbase = by * 256;
    const int nbase = bx * 128;

    // staging source (thread t covers LDS slots t and 512+t per matrix)
    const int arow_g = t512 & 255;
    const int aks_g  = t512 >> 8;
    const unsigned short* gA0 =
        xb + (size_t)(mbase + arow_g) * D_IN + aks_g * 8;
    const int be  = arow_g >> 7;
    const int bcl = nbase + (arow_g & 127);
    const unsigned short* gB0 =
        wbT + ((size_t)be * D_HID + bcl) * D_IN + aks_g * 8;

    // ds_read bases (slot units)
    const int aks  = (lane >> 4) * 256;
    const int arow = wm * 128 + (lane & 15);
    const int brow = wn * 64 + (lane & 15);

    f32x4 acc[8][4];
#pragma unroll
    for (int mi = 0; mi < 8; ++mi)
#pragma unroll
        for (int ni = 0; ni < 4; ++ni) acc[mi][ni] = (f32x4){0.f, 0.f, 0.f, 0.f};

    // prologue: stage tiles 0,1,2
    STAGE_A(0, 0);     STAGE_B(0, 0);
    STAGE_A(2048, 32); STAGE_B(2048, 32);
    STAGE_A(4096, 64); STAGE_B(4096, 64);
    asm volatile("s_waitcnt vmcnt(8)" ::: "memory");
    __builtin_amdgcn_s_barrier();

#pragma unroll 4
    for (int t = 0; t < 61; ++t) {
        TILE(t & 3, (t + 3) & 3, (t + 3) * 32, 1, "s_waitcnt vmcnt(8)");
    }
    TILE(1, 0, 0, 0, "s_waitcnt vmcnt(4)");
    TILE(2, 0, 0, 0, "s_waitcnt vmcnt(0)");
    TILE(3, 0, 0, 0, "s_waitcnt vmcnt(0)");

    // -------- epilogue: combine experts through LDS (f32) --------
    __syncthreads();
    float* fl = (float*)lds;
    if (wn >= 2) {
        float* reg = fl + (wm * 2 + (wn - 2)) * 8192;   // [128][64]
#pragma unroll
        for (int mi = 0; mi < 8; ++mi)
#pragma unroll
            for (int ni = 0; ni < 4; ++ni)
#pragma unroll
                for (int j = 0; j < 4; ++j) {
                    int row_l = mi * 16 + ((lane >> 4) << 2) + j;
                    int col_l = ni * 16 + (lane & 15);
                    reg[row_l * 64 + col_l] = acc[mi][ni][j];
                }
    }
    __syncthreads();
    if (wn < 2) {
        const float* reg = fl + (wm * 2 + wn) * 8192;
        const int e0 = eidx[0], e1 = eidx[1];
        const float* bb0 = b_exp + (size_t)e0 * D_HID;
        const float* bb1 = b_exp + (size_t)e1 * D_HID;
        const float2* s12v = (const float2*)s12;
        int   cc[4];
        float b0c[4], b1c[4];
#pragma unroll
        for (int ni = 0; ni < 4; ++ni) {
            cc[ni]  = nbase + wn * 64 + ni * 16 + (lane & 15);
            b0c[ni] = bb0[cc[ni]];
            b1c[ni] = bb1[cc[ni]];
        }
#pragma unroll
        for (int mi = 0; mi < 8; ++mi)
#pragma unroll
            for (int j = 0; j < 4; ++j) {
                int row_l = mi * 16 + ((lane >> 4) << 2) + j;
                int r = mbase + wm * 128 + row_l;
                float2 s = s12v[r];
#pragma unroll
                for (int ni = 0; ni < 4; ++ni) {
                    float y1 = reg[row_l * 64 + ni * 16 + (lane & 15)];
                    out[(size_t)r * D_HID + cc[ni]] =
                        s.x * (acc[mi][ni][j] + b0c[ni]) + s.y * (y1 + b1c[ni]);
                }
            }
    }
}

// ---------------------------------------------------------------- launch --
extern "C" void kernel_launch(void* const* d_in, const int* in_sizes, int n_in,
                              void* d_out, int out_size, void* d_ws, size_t ws_size,
                              hipStream_t stream) {
    const float* x         = (const float*)d_in[0];
    const float* W_experts = (const float*)d_in[1];
    const float* b_experts = (const float*)d_in[2];
    const float* W_gate    = (const float*)d_in[3];
    const float* b_gate    = (const float*)d_in[4];
    float* out = (float*)d_out;

    char* ws = (char*)d_ws;
    float* s12  = (float*)ws;                                        // 128 KiB
    int*   eidx = (int*)(ws + 131072);
    unsigned short* xb  = (unsigned short*)(ws + 262144);            // 64 MiB
    unsigned short* wbT = (unsigned short*)(ws + 262144 + 67108864); // 16 MiB

    gate_xconv_kernel<<<N_TOK, 256, 0, stream>>>(x, W_gate, b_gate, xb, s12, eidx);
    wconv_kernel<<<dim3(32, 32, 2), 256, 0, stream>>>(W_experts, eidx, wbT);
    moe_gemm_kernel<<<1024, 512, 0, stream>>>(xb, wbT, b_experts, eidx, s12, out);
}

// Round 4
// 519.427 us; speedup vs baseline: 1.0458x; 1.0458x over previous
//
#include <hip/hip_runtime.h>
#include <hip/hip_bf16.h>
#include <stdint.h>

#define N_TOK 16384
#define D_IN  2048
#define D_HID 2048

typedef __attribute__((ext_vector_type(8)))  short bf16x8;
typedef __attribute__((ext_vector_type(4)))  float f32x4;
typedef __attribute__((ext_vector_type(16))) float f32x16;
typedef __attribute__((ext_vector_type(8)))  unsigned short u16x8;

__device__ __forceinline__ unsigned short f2bf(float f) {
    unsigned int u = __float_as_uint(f);
    u = (u + 0x7FFFu + ((u >> 16) & 1u)) >> 16;
    return (unsigned short)u;
}

// ---------------------------------------------------------------- gate ----
__global__ void gate_kernel(const float* __restrict__ x,
                            const float* __restrict__ Wg,
                            const float* __restrict__ bg,
                            float* __restrict__ s12,
                            int* __restrict__ eidx) {
    const int token = blockIdx.x * 4 + (threadIdx.x >> 6);
    const int lane  = threadIdx.x & 63;
    const float* xr = x + (size_t)token * D_IN;

    float acc[8];
#pragma unroll
    for (int e = 0; e < 8; ++e) acc[e] = 0.f;

    for (int i = lane; i < D_IN; i += 64) {
        float xv = xr[i];
        const float4* wr = (const float4*)(Wg + (size_t)i * 8);
        float4 w0 = wr[0], w1 = wr[1];
        acc[0] += xv * w0.x; acc[1] += xv * w0.y;
        acc[2] += xv * w0.z; acc[3] += xv * w0.w;
        acc[4] += xv * w1.x; acc[5] += xv * w1.y;
        acc[6] += xv * w1.z; acc[7] += xv * w1.w;
    }
#pragma unroll
    for (int off = 32; off > 0; off >>= 1) {
#pragma unroll
        for (int e = 0; e < 8; ++e) acc[e] += __shfl_xor(acc[e], off);
    }

    float lg[8];
    float mx = -1e30f;
#pragma unroll
    for (int e = 0; e < 8; ++e) { lg[e] = acc[e] + bg[e]; mx = fmaxf(mx, lg[e]); }
    float sum = 0.f;
#pragma unroll
    for (int e = 0; e < 8; ++e) { lg[e] = expf(lg[e] - mx); sum += lg[e]; }
    float inv = 1.f / sum;

    float s1 = -1.f, s2 = -1.f; int i1 = 0, i2 = 0;
#pragma unroll
    for (int e = 0; e < 8; ++e) {
        float g = lg[e] * inv;
        if (g > s1)      { s2 = s1; i2 = i1; s1 = g; i1 = e; }
        else if (g > s2) { s2 = g;  i2 = e; }
    }
    if (lane == 0) {
        s12[token * 2]     = s1;
        s12[token * 2 + 1] = s2;
        if (token == 0) { eidx[0] = i1; eidx[1] = i2; }
    }
}

// ------------------------------------------------------------- x -> bf16 --
__global__ void xconv_kernel(const float* __restrict__ x,
                             unsigned short* __restrict__ xb) {
    const int total = N_TOK * D_IN / 8;
    for (int idx = blockIdx.x * blockDim.x + threadIdx.x; idx < total;
         idx += gridDim.x * blockDim.x) {
        const float4* s = (const float4*)(x + (size_t)idx * 8);
        float4 a = s[0], b = s[1];
        u16x8 v;
        v[0] = f2bf(a.x); v[1] = f2bf(a.y); v[2] = f2bf(a.z); v[3] = f2bf(a.w);
        v[4] = f2bf(b.x); v[5] = f2bf(b.y); v[6] = f2bf(b.z); v[7] = f2bf(b.w);
        *(u16x8*)(xb + (size_t)idx * 8) = v;
    }
}

// --------------------------------------- W[e0],W[e1] -> bf16 transposed --
__global__ void wconv_kernel(const float* __restrict__ W,
                             const int* __restrict__ eidx,
                             unsigned short* __restrict__ wbT) {
    __shared__ float tile[64][65];
    const int slot = blockIdx.z;
    const int e    = eidx[slot];
    const int k0   = blockIdx.y * 64;
    const int n0   = blockIdx.x * 64;
    const float* src = W + (size_t)e * D_IN * D_HID;
    const int t = threadIdx.x;

#pragma unroll
    for (int p = 0; p < 4; ++p) {
        int row = p * 16 + (t >> 4);
        int col = (t & 15) * 4;
        const float* s = src + (size_t)(k0 + row) * D_HID + n0 + col;
        tile[row][col]     = s[0];
        tile[row][col + 1] = s[1];
        tile[row][col + 2] = s[2];
        tile[row][col + 3] = s[3];
    }
    __syncthreads();

    unsigned short* dst = wbT + (size_t)slot * D_IN * D_HID;
#pragma unroll
    for (int p = 0; p < 2; ++p) {
        int n = p * 32 + (t >> 3);
        int g = (t & 7) * 8;
        u16x8 v;
#pragma unroll
        for (int j = 0; j < 8; ++j) v[j] = f2bf(tile[g + j][n]);
        *(u16x8*)(dst + (size_t)(n0 + n) * D_IN + k0 + g) = v;
    }
}

// ------------------------------------------------------------------ GEMM --
// 256 rows x (128 cols x 2 experts), BK=32, 4 LDS buffers, depth-3 counted
// vmcnt. 32x32x16 MFMA: 16 MFMA per K-tile per wave (4mi x 2ni x 2kk),
// ONE barrier per K-tile, no scheduling pins: compiler emits fine-grained
// lgkmcnt so MFMAs start as operands land and waves skew (overlap LDS drain
// with other waves' MFMA).
#define GLD16(gp, lp)                                                        \
    __builtin_amdgcn_global_load_lds(                                        \
        (const __attribute__((address_space(1))) void*)(gp),                 \
        (__attribute__((address_space(3))) void*)(lp), 16, 0, 0)

#define LDSV(SLOT) (*(const bf16x8*)&lds[(SLOT) * 8])

#define STAGE_A(SBAS, KOFF)                                                  \
    do {                                                                     \
        GLD16(gA0 + (KOFF),      &lds[((SBAS) + t512) * 8]);                 \
        GLD16(gA0 + (KOFF) + 16, &lds[((SBAS) + 512 + t512) * 8]);           \
    } while (0)
#define STAGE_B(SBAS, KOFF)                                                  \
    do {                                                                     \
        GLD16(gB0 + (KOFF),      &lds[((SBAS) + 1024 + t512) * 8]);          \
        GLD16(gB0 + (KOFF) + 16, &lds[((SBAS) + 1536 + t512) * 8]);          \
    } while (0)

// One K-tile: 12 ds_read_b128, optional 4 global_load_lds, vmcnt(N),
// barrier, 16 x mfma_32x32x16.
#define TILE(RB, SB, KOFF, DO_STAGE, VMSTR)                                  \
    do {                                                                     \
        const int rbas = (RB) * 2048;                                        \
        bf16x8 a[4][2], b[2][2];                                             \
        _Pragma("unroll")                                                    \
        for (int kk = 0; kk < 2; ++kk) {                                     \
            _Pragma("unroll")                                                \
            for (int ni = 0; ni < 2; ++ni)                                   \
                b[ni][kk] = LDSV(rbas + bbase + kk * 512 + ni * 32);         \
            _Pragma("unroll")                                                \
            for (int mi = 0; mi < 4; ++mi)                                   \
                a[mi][kk] = LDSV(rbas + abase + kk * 512 + mi * 32);         \
        }                                                                    \
        if (DO_STAGE) { STAGE_A((SB) * 2048, KOFF); STAGE_B((SB) * 2048, KOFF); } \
        asm volatile(VMSTR ::: "memory");                                    \
        __builtin_amdgcn_s_barrier();                                        \
        __builtin_amdgcn_s_setprio(1);                                       \
        _Pragma("unroll")                                                    \
        for (int kk = 0; kk < 2; ++kk)                                       \
            _Pragma("unroll")                                                \
            for (int mi = 0; mi < 4; ++mi)                                   \
                _Pragma("unroll")                                            \
                for (int ni = 0; ni < 2; ++ni)                               \
                    acc[mi][ni] = __builtin_amdgcn_mfma_f32_32x32x16_bf16(   \
                        a[mi][kk], b[ni][kk], acc[mi][ni], 0, 0, 0);         \
        __builtin_amdgcn_s_setprio(0);                                       \
    } while (0)

__global__ __launch_bounds__(512, 2) void moe_gemm_kernel(
    const unsigned short* __restrict__ xb,   // [N_TOK][D_IN] bf16
    const unsigned short* __restrict__ wbT,  // [2][D_HID][D_IN] bf16 (B^T)
    const float* __restrict__ b_exp,         // [8][D_HID]
    const int* __restrict__ eidx,
    const float* __restrict__ s12,           // [N_TOK][2]
    float* __restrict__ out) {
    // 4 buffers x (A:1024 + B:1024 slots) x 16B = 128 KiB
    __shared__ __align__(16) short lds[4 * 2048 * 8];

    const int t512 = threadIdx.x;
    const int lane = t512 & 63;
    const int w    = t512 >> 6;
    const int wm   = w >> 2;      // 0..1 : row half
    const int wn   = w & 3;       // 0..1 expert0 cols, 2..3 expert1 cols
    const int ls   = lane >> 5;   // k-half within fragment
    const int lr   = lane & 31;   // row/col within 32

    // XCD-aware bijective swizzle (1024 % 8 == 0)
    const int bid = blockIdx.x;
    const int wg  = (bid & 7) * 128 + (bid >> 3);
    const int by  = wg >> 4;
    const int bx  = wg & 15;
    const int mbase = by * 256;
    const int nbase = bx * 128;

    // staging source (thread t covers LDS slots t and 512+t per matrix)
    const int arow_g = t512 & 255;
    const int aks_g  = t512 >> 8;
    const unsigned short* gA0 =
        xb + (size_t)(mbase + arow_g) * D_IN + aks_g * 8;
    const int be  = arow_g >> 7;
    const int bcl = nbase + (arow_g & 127);
    const unsigned short* gB0 =
        wbT + ((size_t)be * D_HID + bcl) * D_IN + aks_g * 8;

    // ds_read bases (slot units): slot = (kk*2+ls)*256 + row
    const int abase = ls * 256 + wm * 128 + lr;
    const int bbase = 1024 + ls * 256 + wn * 64 + lr;

    f32x16 acc[4][2];
#pragma unroll
    for (int mi = 0; mi < 4; ++mi)
#pragma unroll
        for (int ni = 0; ni < 2; ++ni)
#pragma unroll
            for (int r = 0; r < 16; ++r) acc[mi][ni][r] = 0.f;

    // prologue: stage tiles 0,1,2
    STAGE_A(0, 0);     STAGE_B(0, 0);
    STAGE_A(2048, 32); STAGE_B(2048, 32);
    STAGE_A(4096, 64); STAGE_B(4096, 64);
    asm volatile("s_waitcnt vmcnt(8)" ::: "memory");
    __builtin_amdgcn_s_barrier();

#pragma unroll 4
    for (int t = 0; t < 61; ++t) {
        TILE(t & 3, (t + 3) & 3, (t + 3) * 32, 1, "s_waitcnt vmcnt(8)");
    }
    TILE(1, 0, 0, 0, "s_waitcnt vmcnt(4)");
    TILE(2, 0, 0, 0, "s_waitcnt vmcnt(0)");
    TILE(3, 0, 0, 0, "s_waitcnt vmcnt(0)");

    // -------- epilogue: combine experts through LDS (f32) --------
    // 32x32 C/D layout: row=(r&3)+8*(r>>2)+4*ls, col=lr (m74/m101).
    __syncthreads();
    float* fl = (float*)lds;
    if (wn >= 2) {
        float* reg = fl + (wm * 2 + (wn - 2)) * 8192;   // [128][64]
#pragma unroll
        for (int mi = 0; mi < 4; ++mi)
#pragma unroll
            for (int ni = 0; ni < 2; ++ni)
#pragma unroll
                for (int r = 0; r < 16; ++r) {
                    int row_l = mi * 32 + (r & 3) + 8 * (r >> 2) + 4 * ls;
                    reg[row_l * 64 + ni * 32 + lr] = acc[mi][ni][r];
                }
    }
    __syncthreads();
    if (wn < 2) {
        const float* reg = fl + (wm * 2 + wn) * 8192;
        const int e0 = eidx[0], e1 = eidx[1];
        const float* bb0 = b_exp + (size_t)e0 * D_HID;
        const float* bb1 = b_exp + (size_t)e1 * D_HID;
        const float2* s12v = (const float2*)s12;
        int   cc[2];
        float b0c[2], b1c[2];
#pragma unroll
        for (int ni = 0; ni < 2; ++ni) {
            cc[ni]  = nbase + wn * 64 + ni * 32 + lr;
            b0c[ni] = bb0[cc[ni]];
            b1c[ni] = bb1[cc[ni]];
        }
#pragma unroll
        for (int mi = 0; mi < 4; ++mi)
#pragma unroll
            for (int r = 0; r < 16; ++r) {
                int row_l = mi * 32 + (r & 3) + 8 * (r >> 2) + 4 * ls;
                int rg = mbase + wm * 128 + row_l;
                float2 s = s12v[rg];
#pragma unroll
                for (int ni = 0; ni < 2; ++ni) {
                    float y1 = reg[row_l * 64 + ni * 32 + lr];
                    out[(size_t)rg * D_HID + cc[ni]] =
                        s.x * (acc[mi][ni][r] + b0c[ni]) + s.y * (y1 + b1c[ni]);
                }
            }
    }
}

// ---------------------------------------------------------------- launch --
extern "C" void kernel_launch(void* const* d_in, const int* in_sizes, int n_in,
                              void* d_out, int out_size, void* d_ws, size_t ws_size,
                              hipStream_t stream) {
    const float* x         = (const float*)d_in[0];
    const float* W_experts = (const float*)d_in[1];
    const float* b_experts = (const float*)d_in[2];
    const float* W_gate    = (const float*)d_in[3];
    const float* b_gate    = (const float*)d_in[4];
    float* out = (float*)d_out;

    char* ws = (char*)d_ws;
    float* s12  = (float*)ws;                                        // 128 KiB
    int*   eidx = (int*)(ws + 131072);
    unsigned short* xb  = (unsigned short*)(ws + 262144);            // 64 MiB
    unsigned short* wbT = (unsigned short*)(ws + 262144 + 67108864); // 16 MiB

    gate_kernel<<<N_TOK / 4, 256, 0, stream>>>(x, W_gate, b_gate, s12, eidx);
    xconv_kernel<<<4096, 256, 0, stream>>>(x, xb);
    wconv_kernel<<<dim3(32, 32, 2), 256, 0, stream>>>(W_experts, eidx, wbT);
    moe_gemm_kernel<<<1024, 512, 0, stream>>>(xb, wbT, b_experts, eidx, s12, out);
}

// Round 5
// 472.941 us; speedup vs baseline: 1.1486x; 1.0983x over previous
//
#include <hip/hip_runtime.h>
#include <hip/hip_bf16.h>
#include <stdint.h>

#define N_TOK 16384
#define D_IN  2048
#define D_HID 2048

typedef __attribute__((ext_vector_type(8))) short  bf16x8;
typedef __attribute__((ext_vector_type(4))) float  f32x4;
typedef __attribute__((ext_vector_type(8))) unsigned short u16x8;

__device__ __forceinline__ unsigned short f2bf(float f) {
    unsigned int u = __float_as_uint(f);
    u = (u + 0x7FFFu + ((u >> 16) & 1u)) >> 16;
    return (unsigned short)u;
}

// ---------------------------------------------------------------- gate ----
__global__ void gate_kernel(const float* __restrict__ x,
                            const float* __restrict__ Wg,
                            const float* __restrict__ bg,
                            float* __restrict__ s12,
                            int* __restrict__ eidx) {
    const int token = blockIdx.x * 4 + (threadIdx.x >> 6);
    const int lane  = threadIdx.x & 63;
    const float* xr = x + (size_t)token * D_IN;

    float acc[8];
#pragma unroll
    for (int e = 0; e < 8; ++e) acc[e] = 0.f;

    for (int i = lane; i < D_IN; i += 64) {
        float xv = xr[i];
        const float4* wr = (const float4*)(Wg + (size_t)i * 8);
        float4 w0 = wr[0], w1 = wr[1];
        acc[0] += xv * w0.x; acc[1] += xv * w0.y;
        acc[2] += xv * w0.z; acc[3] += xv * w0.w;
        acc[4] += xv * w1.x; acc[5] += xv * w1.y;
        acc[6] += xv * w1.z; acc[7] += xv * w1.w;
    }
#pragma unroll
    for (int off = 32; off > 0; off >>= 1) {
#pragma unroll
        for (int e = 0; e < 8; ++e) acc[e] += __shfl_xor(acc[e], off);
    }

    float lg[8];
    float mx = -1e30f;
#pragma unroll
    for (int e = 0; e < 8; ++e) { lg[e] = acc[e] + bg[e]; mx = fmaxf(mx, lg[e]); }
    float sum = 0.f;
#pragma unroll
    for (int e = 0; e < 8; ++e) { lg[e] = expf(lg[e] - mx); sum += lg[e]; }
    float inv = 1.f / sum;

    float s1 = -1.f, s2 = -1.f; int i1 = 0, i2 = 0;
#pragma unroll
    for (int e = 0; e < 8; ++e) {
        float g = lg[e] * inv;
        if (g > s1)      { s2 = s1; i2 = i1; s1 = g; i1 = e; }
        else if (g > s2) { s2 = g;  i2 = e; }
    }
    if (lane == 0) {
        s12[token * 2]     = s1;
        s12[token * 2 + 1] = s2;
        if (token == 0) { eidx[0] = i1; eidx[1] = i2; }
    }
}

// ------------------------------------------------------------- x -> bf16 --
__global__ void xconv_kernel(const float* __restrict__ x,
                             unsigned short* __restrict__ xb) {
    const int total = N_TOK * D_IN / 8;
    for (int idx = blockIdx.x * blockDim.x + threadIdx.x; idx < total;
         idx += gridDim.x * blockDim.x) {
        const float4* s = (const float4*)(x + (size_t)idx * 8);
        float4 a = s[0], b = s[1];
        u16x8 v;
        v[0] = f2bf(a.x); v[1] = f2bf(a.y); v[2] = f2bf(a.z); v[3] = f2bf(a.w);
        v[4] = f2bf(b.x); v[5] = f2bf(b.y); v[6] = f2bf(b.z); v[7] = f2bf(b.w);
        *(u16x8*)(xb + (size_t)idx * 8) = v;
    }
}

// --------------------------------------- W[e0],W[e1] -> bf16 transposed --
__global__ void wconv_kernel(const float* __restrict__ W,
                             const int* __restrict__ eidx,
                             unsigned short* __restrict__ wbT) {
    __shared__ float tile[64][65];
    const int slot = blockIdx.z;
    const int e    = eidx[slot];
    const int k0   = blockIdx.y * 64;
    const int n0   = blockIdx.x * 64;
    const float* src = W + (size_t)e * D_IN * D_HID;
    const int t = threadIdx.x;

#pragma unroll
    for (int p = 0; p < 4; ++p) {
        int row = p * 16 + (t >> 4);
        int col = (t & 15) * 4;
        const float* s = src + (size_t)(k0 + row) * D_HID + n0 + col;
        tile[row][col]     = s[0];
        tile[row][col + 1] = s[1];
        tile[row][col + 2] = s[2];
        tile[row][col + 3] = s[3];
    }
    __syncthreads();

    unsigned short* dst = wbT + (size_t)slot * D_IN * D_HID;
#pragma unroll
    for (int p = 0; p < 2; ++p) {
        int n = p * 32 + (t >> 3);
        int g = (t & 7) * 8;
        u16x8 v;
#pragma unroll
        for (int j = 0; j < 8; ++j) v[j] = f2bf(tile[g + j][n]);
        *(u16x8*)(dst + (size_t)(n0 + n) * D_IN + k0 + g) = v;
    }
}

// ------------------------------------------------------------------ GEMM --
// 256 rows x (128 cols x 2 experts), BK=32, 4 LDS buffers, depth-3 staging.
// Per K-tile: 12 ds_reads issued BEFORE the tile-start barrier (latency
// hides under barrier wait); compiler's fine-grained lgkmcnt gates each
// MFMA cluster (no asm lgkm0, no sched pins); counted vmcnt(6) after MFMA1
// issue retires exactly tile-(t+1)'s A+B loads, globally fenced at the mid
// barrier. Formal chain: reads(t+1) <- midbar(t) <- all waves' vmcnt(6)(t)
// <- (t+1) loads retired.
#define GLD16(gp, lp)                                                        \
    __builtin_amdgcn_global_load_lds(                                        \
        (const __attribute__((address_space(1))) void*)(gp),                 \
        (__attribute__((address_space(3))) void*)(lp), 16, 0, 0)

#define LDSV(SLOT) (*(const bf16x8*)&lds[(SLOT) * 8])

#define STAGE_A(SBAS, KOFF)                                                  \
    do {                                                                     \
        GLD16(gA0 + (KOFF),      &lds[((SBAS) + t512) * 8]);                 \
        GLD16(gA0 + (KOFF) + 16, &lds[((SBAS) + 512 + t512) * 8]);           \
    } while (0)
#define STAGE_B(SBAS, KOFF)                                                  \
    do {                                                                     \
        GLD16(gB0 + (KOFF),      &lds[((SBAS) + 1024 + t512) * 8]);          \
        GLD16(gB0 + (KOFF) + 16, &lds[((SBAS) + 1536 + t512) * 8]);          \
    } while (0)

#define MF(MI, AV)                                                                              \
    acc[MI][0] = __builtin_amdgcn_mfma_f32_16x16x32_bf16(AV, bf0, acc[MI][0], 0, 0, 0);         \
    acc[MI][1] = __builtin_amdgcn_mfma_f32_16x16x32_bf16(AV, bf1, acc[MI][1], 0, 0, 0);         \
    acc[MI][2] = __builtin_amdgcn_mfma_f32_16x16x32_bf16(AV, bf2, acc[MI][2], 0, 0, 0);         \
    acc[MI][3] = __builtin_amdgcn_mfma_f32_16x16x32_bf16(AV, bf3, acc[MI][3], 0, 0, 0);

#define TILE(RB, SB, KOFF, DO_STAGE, VMSTR)                                  \
    do {                                                                     \
        const int rbas  = (RB) * 2048;                                       \
        const int abase = rbas + aks + arow;                                 \
        const int bbase = rbas + 1024 + aks + brow;                          \
        bf16x8 bf0 = LDSV(bbase), bf1 = LDSV(bbase + 16),                    \
               bf2 = LDSV(bbase + 32), bf3 = LDSV(bbase + 48);               \
        bf16x8 a0 = LDSV(abase), a1 = LDSV(abase + 16),                      \
               a2 = LDSV(abase + 32), a3 = LDSV(abase + 48);                 \
        bf16x8 a4 = LDSV(abase + 64), a5 = LDSV(abase + 80),                 \
               a6 = LDSV(abase + 96), a7 = LDSV(abase + 112);                \
        __builtin_amdgcn_s_barrier();                                        \
        if (DO_STAGE) STAGE_A((SB) * 2048, KOFF);                            \
        __builtin_amdgcn_s_setprio(1);                                       \
        MF(0, a0) MF(1, a1) MF(2, a2) MF(3, a3)                              \
        __builtin_amdgcn_s_setprio(0);                                       \
        asm volatile(VMSTR ::: "memory");                                    \
        __builtin_amdgcn_s_barrier();                                        \
        if (DO_STAGE) STAGE_B((SB) * 2048, KOFF);                            \
        __builtin_amdgcn_s_setprio(1);                                       \
        MF(4, a4) MF(5, a5) MF(6, a6) MF(7, a7)                              \
        __builtin_amdgcn_s_setprio(0);                                       \
    } while (0)

__global__ __launch_bounds__(512, 2) void moe_gemm_kernel(
    const unsigned short* __restrict__ xb,   // [N_TOK][D_IN] bf16
    const unsigned short* __restrict__ wbT,  // [2][D_HID][D_IN] bf16 (B^T)
    const float* __restrict__ b_exp,         // [8][D_HID]
    const int* __restrict__ eidx,
    const float* __restrict__ s12,           // [N_TOK][2]
    float* __restrict__ out) {
    // 4 buffers x (A:1024 + B:1024 slots) x 16B = 128 KiB
    __shared__ __align__(16) short lds[4 * 2048 * 8];

    const int t512 = threadIdx.x;
    const int lane = t512 & 63;
    const int w    = t512 >> 6;
    const int wm   = w >> 2;      // 0..1 : row half
    const int wn   = w & 3;       // 0..1 expert0 cols, 2..3 expert1 cols

    // XCD-aware bijective swizzle (1024 % 8 == 0)
    const int bid = blockIdx.x;
    const int wg  = (bid & 7) * 128 + (bid >> 3);
    const int by  = wg >> 4;
    const int bx  = wg & 15;
    const int mbase = by * 256;
    const int nbase = bx * 128;

    // staging source (thread t covers LDS slots t and 512+t per matrix)
    const int arow_g = t512 & 255;
    const int aks_g  = t512 >> 8;
    const unsigned short* gA0 =
        xb + (size_t)(mbase + arow_g) * D_IN + aks_g * 8;
    const int be  = arow_g >> 7;
    const int bcl = nbase + (arow_g & 127);
    const unsigned short* gB0 =
        wbT + ((size_t)be * D_HID + bcl) * D_IN + aks_g * 8;

    // ds_read bases (slot units): slot = kslot*256 + row
    const int aks  = (lane >> 4) * 256;
    const int arow = wm * 128 + (lane & 15);
    const int brow = wn * 64 + (lane & 15);

    f32x4 acc[8][4];
#pragma unroll
    for (int mi = 0; mi < 8; ++mi)
#pragma unroll
        for (int ni = 0; ni < 4; ++ni) acc[mi][ni] = (f32x4){0.f, 0.f, 0.f, 0.f};

    // prologue: stage tiles 0,1,2 (12 loads); vmcnt(8) retires tile-0's 4.
    STAGE_A(0, 0);     STAGE_B(0, 0);
    STAGE_A(2048, 32); STAGE_B(2048, 32);
    STAGE_A(4096, 64); STAGE_B(4096, 64);
    asm volatile("s_waitcnt vmcnt(8)" ::: "memory");
    __builtin_amdgcn_s_barrier();

#pragma unroll 4
    for (int t = 0; t < 61; ++t) {
        TILE(t & 3, (t + 3) & 3, (t + 3) * 32, 1, "s_waitcnt vmcnt(6)");
    }
    TILE(1, 0, 0, 0, "s_waitcnt vmcnt(4)");
    TILE(2, 0, 0, 0, "s_waitcnt vmcnt(0)");
    TILE(3, 0, 0, 0, "s_waitcnt vmcnt(0)");

    // -------- epilogue: combine experts through LDS (f32) --------
    __syncthreads();
    float* fl = (float*)lds;
    if (wn >= 2) {
        float* reg = fl + (wm * 2 + (wn - 2)) * 8192;   // [128][64]
#pragma unroll
        for (int mi = 0; mi < 8; ++mi)
#pragma unroll
            for (int ni = 0; ni < 4; ++ni)
#pragma unroll
                for (int j = 0; j < 4; ++j) {
                    int row_l = mi * 16 + ((lane >> 4) << 2) + j;
                    int col_l = ni * 16 + (lane & 15);
                    reg[row_l * 64 + col_l] = acc[mi][ni][j];
                }
    }
    __syncthreads();
    if (wn < 2) {
        const float* reg = fl + (wm * 2 + wn) * 8192;
        const int e0 = eidx[0], e1 = eidx[1];
        const float* bb0 = b_exp + (size_t)e0 * D_HID;
        const float* bb1 = b_exp + (size_t)e1 * D_HID;
        const float2* s12v = (const float2*)s12;
        int   cc[4];
        float b0c[4], b1c[4];
#pragma unroll
        for (int ni = 0; ni < 4; ++ni) {
            cc[ni]  = nbase + wn * 64 + ni * 16 + (lane & 15);
            b0c[ni] = bb0[cc[ni]];
            b1c[ni] = bb1[cc[ni]];
        }
#pragma unroll
        for (int mi = 0; mi < 8; ++mi)
#pragma unroll
            for (int j = 0; j < 4; ++j) {
                int row_l = mi * 16 + ((lane >> 4) << 2) + j;
                int r = mbase + wm * 128 + row_l;
                float2 s = s12v[r];
#pragma unroll
                for (int ni = 0; ni < 4; ++ni) {
                    float y1 = reg[row_l * 64 + ni * 16 + (lane & 15)];
                    out[(size_t)r * D_HID + cc[ni]] =
                        s.x * (acc[mi][ni][j] + b0c[ni]) + s.y * (y1 + b1c[ni]);
                }
            }
    }
}

// ---------------------------------------------------------------- launch --
extern "C" void kernel_launch(void* const* d_in, const int* in_sizes, int n_in,
                              void* d_out, int out_size, void* d_ws, size_t ws_size,
                              hipStream_t stream) {
    const float* x         = (const float*)d_in[0];
    const float* W_experts = (const float*)d_in[1];
    const float* b_experts = (const float*)d_in[2];
    const float* W_gate    = (const float*)d_in[3];
    const float* b_gate    = (const float*)d_in[4];
    float* out = (float*)d_out;

    char* ws = (char*)d_ws;
    float* s12  = (float*)ws;                                        // 128 KiB
    int*   eidx = (int*)(ws + 131072);
    unsigned short* xb  = (unsigned short*)(ws + 262144);            // 64 MiB
    unsigned short* wbT = (unsigned short*)(ws + 262144 + 67108864); // 16 MiB

    gate_kernel<<<N_TOK / 4, 256, 0, stream>>>(x, W_gate, b_gate, s12, eidx);
    xconv_kernel<<<4096, 256, 0, stream>>>(x, xb);
    wconv_kernel<<<dim3(32, 32, 2), 256, 0, stream>>>(W_experts, eidx, wbT);
    moe_gemm_kernel<<<1024, 512, 0, stream>>>(xb, wbT, b_experts, eidx, s12, out);
}

// Round 6
// 323.015 us; speedup vs baseline: 1.6818x; 1.4641x over previous
//
#include <hip/hip_runtime.h>
#include <hip/hip_bf16.h>
#include <stdint.h>

#define N_TOK 16384
#define D_IN  2048
#define D_HID 2048

typedef __attribute__((ext_vector_type(8))) short  bf16x8;
typedef __attribute__((ext_vector_type(4))) float  f32x4;
typedef __attribute__((ext_vector_type(8))) unsigned short u16x8;

__device__ __forceinline__ unsigned short f2bf(float f) {
    unsigned int u = __float_as_uint(f);
    u = (u + 0x7FFFu + ((u >> 16) & 1u)) >> 16;
    return (unsigned short)u;
}

// ---------------------------------------------------------------- gate ----
__global__ void gate_kernel(const float* __restrict__ x,
                            const float* __restrict__ Wg,
                            const float* __restrict__ bg,
                            float* __restrict__ s12,
                            int* __restrict__ eidx) {
    const int token = blockIdx.x * 4 + (threadIdx.x >> 6);
    const int lane  = threadIdx.x & 63;
    const float* xr = x + (size_t)token * D_IN;

    float acc[8];
#pragma unroll
    for (int e = 0; e < 8; ++e) acc[e] = 0.f;

    for (int i = lane; i < D_IN; i += 64) {
        float xv = xr[i];
        const float4* wr = (const float4*)(Wg + (size_t)i * 8);
        float4 w0 = wr[0], w1 = wr[1];
        acc[0] += xv * w0.x; acc[1] += xv * w0.y;
        acc[2] += xv * w0.z; acc[3] += xv * w0.w;
        acc[4] += xv * w1.x; acc[5] += xv * w1.y;
        acc[6] += xv * w1.z; acc[7] += xv * w1.w;
    }
#pragma unroll
    for (int off = 32; off > 0; off >>= 1) {
#pragma unroll
        for (int e = 0; e < 8; ++e) acc[e] += __shfl_xor(acc[e], off);
    }

    float lg[8];
    float mx = -1e30f;
#pragma unroll
    for (int e = 0; e < 8; ++e) { lg[e] = acc[e] + bg[e]; mx = fmaxf(mx, lg[e]); }
    float sum = 0.f;
#pragma unroll
    for (int e = 0; e < 8; ++e) { lg[e] = expf(lg[e] - mx); sum += lg[e]; }
    float inv = 1.f / sum;

    float s1 = -1.f, s2 = -1.f; int i1 = 0, i2 = 0;
#pragma unroll
    for (int e = 0; e < 8; ++e) {
        float g = lg[e] * inv;
        if (g > s1)      { s2 = s1; i2 = i1; s1 = g; i1 = e; }
        else if (g > s2) { s2 = g;  i2 = e; }
    }
    if (lane == 0) {
        s12[token * 2]     = s1;
        s12[token * 2 + 1] = s2;
        if (token == 0) { eidx[0] = i1; eidx[1] = i2; }
    }
}

// ------------------------------- x -> bf16, slab order (staging image) ----
// xb_sw[mt][kt] = 16 KB slab of 1024 granules; granule slot = ks*256 + row,
// granule = 8 consecutive k (bf16x8) of token row. Thread t = row: reads
// 128 B contiguous (32 f32), writes 4 granules at slots {ks*256+t} — each
// wave's store = 1 KB contiguous.
__global__ __launch_bounds__(256) void xconv_kernel(
    const float* __restrict__ x, unsigned short* __restrict__ xb) {
    const int mt = blockIdx.x >> 6;
    const int kt = blockIdx.x & 63;
    const int t  = threadIdx.x;
    const float* src = x + ((size_t)(mt * 256 + t)) * D_IN + kt * 32;
    unsigned short* slab = xb + ((size_t)(mt * 64 + kt)) * 8192;
#pragma unroll
    for (int ks = 0; ks < 4; ++ks) {
        float4 a = *(const float4*)(src + ks * 8);
        float4 b = *(const float4*)(src + ks * 8 + 4);
        u16x8 v;
        v[0] = f2bf(a.x); v[1] = f2bf(a.y); v[2] = f2bf(a.z); v[3] = f2bf(a.w);
        v[4] = f2bf(b.x); v[5] = f2bf(b.y); v[6] = f2bf(b.z); v[7] = f2bf(b.w);
        *(u16x8*)(slab + (ks * 256 + t) * 8) = v;
    }
}

// --------------------- W[e0],W[e1] -> bf16 slab order (transposed) --------
// wbT_sw[bx][kt] slab: slot = ks*256 + be*128 + col_local; granule = 8
// consecutive k at fixed output col. LDS transpose tile, slab-ordered
// coalesced writes.
__global__ void wconv_kernel(const float* __restrict__ W,
                             const int* __restrict__ eidx,
                             unsigned short* __restrict__ wbT) {
    __shared__ float tile[64][65];
    const int be  = blockIdx.z;
    const int e   = eidx[be];
    const int k0  = blockIdx.y * 64;          // 32 k-blocks of 64
    const int n0  = blockIdx.x * 64;          // 32 n-blocks of 64
    const int bx  = n0 >> 7;
    const int cl0 = n0 & 127;
    const int kt0 = k0 >> 5;                  // two k-tiles per block
    const float* src = W + (size_t)e * D_IN * D_HID;
    const int t = threadIdx.x;

#pragma unroll
    for (int p = 0; p < 4; ++p) {
        int row = p * 16 + (t >> 4);          // k within block
        int col = (t & 15) * 4;               // n within block
        const float* s = src + (size_t)(k0 + row) * D_HID + n0 + col;
        tile[row][col]     = s[0];
        tile[row][col + 1] = s[1];
        tile[row][col + 2] = s[2];
        tile[row][col + 3] = s[3];
    }
    __syncthreads();

    const int g   = (t >> 5) * 8;             // k base 0..56
    const int ktl = t >> 7;                   // 0,1
    const int ks  = (t >> 5) & 3;
#pragma unroll
    for (int p = 0; p < 2; ++p) {
        int n = p * 32 + (t & 31);
        u16x8 v;
#pragma unroll
        for (int j = 0; j < 8; ++j) v[j] = f2bf(tile[g + j][n]);
        unsigned short* dst = wbT + ((size_t)(bx * 64 + kt0 + ktl)) * 8192 +
                              ((size_t)(ks * 256 + be * 128 + cl0 + n)) * 8;
        *(u16x8*)dst = v;
    }
}

// ------------------------------------------------------------------ GEMM --
// 256 rows x (128 cols x 2 experts), BK=32, 4 LDS buffers, depth-3 counted
// vmcnt(6). Staging sources are PRE-SWIZZLED slabs: src = slab + t*16 ->
// each wave-wide global_load_lds reads 1 KB CONTIGUOUS (was 64 scattered
// 16-B lines -> the R2-R5 invariant stall). LDS image = slab image:
// k-slot-major, 0-conflict ds_reads. XCD swizzle gives each XCD 2 bx
// columns -> B working set 2 MB, L2-resident per XCD.
#define GLD16(gp, lp)                                                        \
    __builtin_amdgcn_global_load_lds(                                        \
        (const __attribute__((address_space(1))) void*)(gp),                 \
        (__attribute__((address_space(3))) void*)(lp), 16, 0, 0)

#define LDSV(SLOT) (*(const bf16x8*)&lds[(SLOT) * 8])

#define STAGE_A(SBAS, KT)                                                    \
    do {                                                                     \
        GLD16(gA0 + (size_t)(KT) * 8192,        &lds[((SBAS) + t512) * 8]);  \
        GLD16(gA0 + (size_t)(KT) * 8192 + 4096, &lds[((SBAS) + 512 + t512) * 8]); \
    } while (0)
#define STAGE_B(SBAS, KT)                                                    \
    do {                                                                     \
        GLD16(gB0 + (size_t)(KT) * 8192,        &lds[((SBAS) + 1024 + t512) * 8]); \
        GLD16(gB0 + (size_t)(KT) * 8192 + 4096, &lds[((SBAS) + 1536 + t512) * 8]); \
    } while (0)

#define MF(MI, AV)                                                                              \
    acc[MI][0] = __builtin_amdgcn_mfma_f32_16x16x32_bf16(AV, bf0, acc[MI][0], 0, 0, 0);         \
    acc[MI][1] = __builtin_amdgcn_mfma_f32_16x16x32_bf16(AV, bf1, acc[MI][1], 0, 0, 0);         \
    acc[MI][2] = __builtin_amdgcn_mfma_f32_16x16x32_bf16(AV, bf2, acc[MI][2], 0, 0, 0);         \
    acc[MI][3] = __builtin_amdgcn_mfma_f32_16x16x32_bf16(AV, bf3, acc[MI][3], 0, 0, 0);

#define TILE(RB, SB, KT, DO_STAGE, VMSTR)                                    \
    do {                                                                     \
        const int rbas  = (RB) * 2048;                                       \
        const int abase = rbas + aks + arow;                                 \
        const int bbase = rbas + 1024 + aks + brow;                          \
        bf16x8 bf0 = LDSV(bbase), bf1 = LDSV(bbase + 16),                    \
               bf2 = LDSV(bbase + 32), bf3 = LDSV(bbase + 48);               \
        bf16x8 a0 = LDSV(abase), a1 = LDSV(abase + 16),                      \
               a2 = LDSV(abase + 32), a3 = LDSV(abase + 48);                 \
        bf16x8 a4 = LDSV(abase + 64), a5 = LDSV(abase + 80),                 \
               a6 = LDSV(abase + 96), a7 = LDSV(abase + 112);                \
        __builtin_amdgcn_s_barrier();                                        \
        if (DO_STAGE) STAGE_A((SB) * 2048, KT);                              \
        __builtin_amdgcn_s_setprio(1);                                       \
        MF(0, a0) MF(1, a1) MF(2, a2) MF(3, a3)                              \
        __builtin_amdgcn_s_setprio(0);                                       \
        asm volatile(VMSTR ::: "memory");                                    \
        __builtin_amdgcn_s_barrier();                                        \
        if (DO_STAGE) STAGE_B((SB) * 2048, KT);                              \
        __builtin_amdgcn_s_setprio(1);                                       \
        MF(4, a4) MF(5, a5) MF(6, a6) MF(7, a7)                              \
        __builtin_amdgcn_s_setprio(0);                                       \
    } while (0)

__global__ __launch_bounds__(512, 2) void moe_gemm_kernel(
    const unsigned short* __restrict__ xb,   // slab order [mt64][kt64][1024]
    const unsigned short* __restrict__ wbT,  // slab order [bx16][kt64][1024]
    const float* __restrict__ b_exp,         // [8][D_HID]
    const int* __restrict__ eidx,
    const float* __restrict__ s12,           // [N_TOK][2]
    float* __restrict__ out) {
    // 4 buffers x (A:1024 + B:1024 slots) x 16B = 128 KiB
    __shared__ __align__(16) short lds[4 * 2048 * 8];

    const int t512 = threadIdx.x;
    const int lane = t512 & 63;
    const int w    = t512 >> 6;
    const int wm   = w >> 2;      // 0..1 : row half
    const int wn   = w & 3;       // 0..1 expert0 cols, 2..3 expert1 cols

    // XCD swizzle for B L2-residency: each XCD owns bx pair {2*xcd, 2*xcd+1}
    // (2 MB of B slabs <= 4 MB per-XCD L2); by walks slowly for A reuse.
    const int bid = blockIdx.x;
    const int xcd = bid & 7;
    const int jb  = bid >> 3;               // 0..127
    const int bx  = xcd * 2 + (jb & 1);     // 0..15
    const int by  = jb >> 1;                // 0..63
    const int mbase = by * 256;
    const int nbase = bx * 128;

    // staging sources: contiguous slabs, thread t covers granules t, t+512
    const unsigned short* gA0 = xb  + ((size_t)by * 64) * 8192 + t512 * 8;
    const unsigned short* gB0 = wbT + ((size_t)bx * 64) * 8192 + t512 * 8;

    // ds_read bases (slot units): slot = kslot*256 + row
    const int aks  = (lane >> 4) * 256;
    const int arow = wm * 128 + (lane & 15);
    const int brow = wn * 64 + (lane & 15);

    f32x4 acc[8][4];
#pragma unroll
    for (int mi = 0; mi < 8; ++mi)
#pragma unroll
        for (int ni = 0; ni < 4; ++ni) acc[mi][ni] = (f32x4){0.f, 0.f, 0.f, 0.f};

    // prologue: stage tiles 0,1,2 (12 loads); vmcnt(8) retires tile-0's 4.
    STAGE_A(0, 0);    STAGE_B(0, 0);
    STAGE_A(2048, 1); STAGE_B(2048, 1);
    STAGE_A(4096, 2); STAGE_B(4096, 2);
    asm volatile("s_waitcnt vmcnt(8)" ::: "memory");
    __builtin_amdgcn_s_barrier();

#pragma unroll 4
    for (int t = 0; t < 61; ++t) {
        TILE(t & 3, (t + 3) & 3, t + 3, 1, "s_waitcnt vmcnt(6)");
    }
    TILE(1, 0, 0, 0, "s_waitcnt vmcnt(4)");
    TILE(2, 0, 0, 0, "s_waitcnt vmcnt(0)");
    TILE(3, 0, 0, 0, "s_waitcnt vmcnt(0)");

    // -------- epilogue: combine experts through LDS (f32) --------
    __syncthreads();
    float* fl = (float*)lds;
    if (wn >= 2) {
        float* reg = fl + (wm * 2 + (wn - 2)) * 8192;   // [128][64]
#pragma unroll
        for (int mi = 0; mi < 8; ++mi)
#pragma unroll
            for (int ni = 0; ni < 4; ++ni)
#pragma unroll
                for (int j = 0; j < 4; ++j) {
                    int row_l = mi * 16 + ((lane >> 4) << 2) + j;
                    int col_l = ni * 16 + (lane & 15);
                    reg[row_l * 64 + col_l] = acc[mi][ni][j];
                }
    }
    __syncthreads();
    if (wn < 2) {
        const float* reg = fl + (wm * 2 + wn) * 8192;
        const int e0 = eidx[0], e1 = eidx[1];
        const float* bb0 = b_exp + (size_t)e0 * D_HID;
        const float* bb1 = b_exp + (size_t)e1 * D_HID;
        const float2* s12v = (const float2*)s12;
        int   cc[4];
        float b0c[4], b1c[4];
#pragma unroll
        for (int ni = 0; ni < 4; ++ni) {
            cc[ni]  = nbase + wn * 64 + ni * 16 + (lane & 15);
            b0c[ni] = bb0[cc[ni]];
            b1c[ni] = bb1[cc[ni]];
        }
#pragma unroll
        for (int mi = 0; mi < 8; ++mi)
#pragma unroll
            for (int j = 0; j < 4; ++j) {
                int row_l = mi * 16 + ((lane >> 4) << 2) + j;
                int r = mbase + wm * 128 + row_l;
                float2 s = s12v[r];
#pragma unroll
                for (int ni = 0; ni < 4; ++ni) {
                    float y1 = reg[row_l * 64 + ni * 16 + (lane & 15)];
                    out[(size_t)r * D_HID + cc[ni]] =
                        s.x * (acc[mi][ni][j] + b0c[ni]) + s.y * (y1 + b1c[ni]);
                }
            }
    }
}

// ---------------------------------------------------------------- launch --
extern "C" void kernel_launch(void* const* d_in, const int* in_sizes, int n_in,
                              void* d_out, int out_size, void* d_ws, size_t ws_size,
                              hipStream_t stream) {
    const float* x         = (const float*)d_in[0];
    const float* W_experts = (const float*)d_in[1];
    const float* b_experts = (const float*)d_in[2];
    const float* W_gate    = (const float*)d_in[3];
    const float* b_gate    = (const float*)d_in[4];
    float* out = (float*)d_out;

    char* ws = (char*)d_ws;
    float* s12  = (float*)ws;                                        // 128 KiB
    int*   eidx = (int*)(ws + 131072);
    unsigned short* xb  = (unsigned short*)(ws + 262144);            // 64 MiB
    unsigned short* wbT = (unsigned short*)(ws + 262144 + 67108864); // 16 MiB

    gate_kernel<<<N_TOK / 4, 256, 0, stream>>>(x, W_gate, b_gate, s12, eidx);
    xconv_kernel<<<4096, 256, 0, stream>>>(x, xb);
    wconv_kernel<<<dim3(32, 32, 2), 256, 0, stream>>>(W_experts, eidx, wbT);
    moe_gemm_kernel<<<1024, 512, 0, stream>>>(xb, wbT, b_experts, eidx, s12, out);
}